// Round 9
// baseline (1096.677 us; speedup 1.0000x reference)
//
#include <hip/hip_runtime.h>
#include <math.h>

#define T_LEN 16000
#define NTILE 250          // time tiles per batch row (16000/64)
#define TT 64              // time tile
#define NBLK 2000          // 8 * 250
#define LGRID 500          // layer grid: 4 strided tiles per block

static const int N_RES = 8 * 32 * T_LEN;   // 4,096,000 floats per residual buffer

typedef _Float16 half_t;
typedef __attribute__((ext_vector_type(8))) _Float16 halfx8;
typedef __attribute__((ext_vector_type(4))) _Float16 halfx4;
typedef __attribute__((ext_vector_type(16))) float f32x16;
typedef unsigned int uint32;
typedef unsigned short ushort16;

#define MFMA(a, b, c) __builtin_amdgcn_mfma_f32_32x32x16_f16((a), (b), (c), 0, 0, 0)

static __device__ inline uint32 packpair(float a, float b) {
  half_t ha = (half_t)a, hb = (half_t)b;
  return (uint32)__builtin_bit_cast(ushort16, ha) |
         ((uint32)__builtin_bit_cast(ushort16, hb) << 16);
}

// ---------------- weight repack ----------------
// WaG[l][o=0..127][k=0..127]: k<64: k=2c+s -> hi(Wd[l][o][c][s]); k>=64: lo*2048 of same
// WrG[l][o2=0..31][k=0..255]: g-register perm; kk=k&127: ks=kk>>4, lh=(kk>>3)&1, j=kk&7;
//   mh=ks>>2, til=(ks>>1)&1, ab=ks&1; m = mh*64+til*32+ab*16+(j&3)+8*(j>>2)+4*lh
//   k<128 hi of Wr[l][m][o2]^T, k>=128 lo*2048  (GEMM2's B-operand = gate regs directly)
// WsS[o=0..31][k=0..511]: k<256 hi Ws[o][k], k>=256 lo*2048
// We1S[o][k=0..63]: k<32 hi We1[o][k], k>=32 lo*2048
// We2S[o][k=0..511]: k<256 hi We2[o][k], k>=256 lo*2048
__global__ __launch_bounds__(256) void repack_k(
    const float* __restrict__ Wd, const float* __restrict__ Wr,
    const float* __restrict__ Ws, const float* __restrict__ We1,
    const float* __restrict__ We2,
    half_t* __restrict__ WaG, half_t* __restrict__ WrG, half_t* __restrict__ WsS,
    half_t* __restrict__ We1S, half_t* __restrict__ We2S) {
  int i = blockIdx.x * 256 + threadIdx.x;
  if (i < 40 * 128 * 128) {
    int l = i >> 14, r = i & 16383, o = r >> 7, k = r & 127;
    int kk = k & 63, c = kk >> 1, s = kk & 1;
    float w = Wd[(((l * 128 + o) * 32 + c) << 1) + s];
    half_t w0 = (half_t)w;
    WaG[i] = (k < 64) ? w0 : (half_t)((w - (float)w0) * 2048.f);
  }
  if (i < 40 * 32 * 256) {
    int l = i >> 13, r = i & 8191, o2 = r >> 8, k = r & 255;
    int kk = k & 127;
    int ks = kk >> 4, lh = (kk >> 3) & 1, j = kk & 7;
    int mh = ks >> 2, til = (ks >> 1) & 1, ab = ks & 1;
    int m = mh * 64 + til * 32 + ab * 16 + (j & 3) + ((j >> 2) << 3) + lh * 4;
    float w = Wr[(l * 32 + o2) * 128 + m];
    half_t w0 = (half_t)w;
    WrG[i] = (k < 128) ? w0 : (half_t)((w - (float)w0) * 2048.f);
  }
  if (i < 16384) {
    int o = i >> 9, k = i & 511, c = k & 255;
    float w = Ws[o * 256 + c];
    half_t w0 = (half_t)w;
    WsS[i] = (k < 256) ? w0 : (half_t)((w - (float)w0) * 2048.f);
  }
  if (i < 16384) {
    int o = i >> 6, k = i & 63;
    float w = We1[o * 32 + (k & 31)];
    half_t w0 = (half_t)w;
    We1S[i] = (k < 32) ? w0 : (half_t)((w - (float)w0) * 2048.f);
  }
  if (i < 131072) {
    int o = i >> 9, k = i & 511;
    float w = We2[o * 256 + (k & 255)];
    half_t w0 = (half_t)w;
    We2S[i] = (k < 256) ? w0 : (half_t)((w - (float)w0) * 2048.f);
  }
}

// ---------------- start 1x1 conv, MFMA split-2: residual = W_start @ x ----------------
// LDS: xs [64 t rows][528B] (256 K-halves + pad, XOR-swizzled) at 0; skb 2x32x68 f32 at 33792
__global__ __launch_bounds__(256, 2) void start_k(const float* __restrict__ x,
                                                  const half_t* __restrict__ WsS,
                                                  float* __restrict__ res) {
  __shared__ __align__(16) char sm[51200];
  const int XS_OFF = 0, SKB_OFF = 33792;
  int tid = threadIdx.x;
  int wave = tid >> 6, lane = tid & 63;
  int l31 = lane & 31, lhi = lane >> 5;
  int nh = wave & 1, kh = wave >> 1;
  int b = blockIdx.x / NTILE;
  int t0 = (blockIdx.x % NTILE) * TT;
  int c2 = tid & 127;            // channel pair (2c2, 2c2+1)
  int th = (tid >> 7) * 32;      // t-half base
  const float* xp0 = x + ((size_t)b * 256 + 2 * c2) * T_LEN + t0 + th;
  const float* xp1 = xp0 + T_LEN;

  f32x16 accH{}, accL{};
#pragma unroll
  for (int p = 0; p < 2; ++p) {
    // ---- stage phase p: p=0 hi halves, p=1 lo halves ----
#pragma unroll
    for (int q = 0; q < 4; ++q) {
      float u[8], v[8];
      *(float4*)u       = *(const float4*)(xp0 + q * 8);
      *(float4*)(u + 4) = *(const float4*)(xp0 + q * 8 + 4);
      *(float4*)v       = *(const float4*)(xp1 + q * 8);
      *(float4*)(v + 4) = *(const float4*)(xp1 + q * 8 + 4);
#pragma unroll
      for (int j = 0; j < 8; ++j) {
        int t = th + q * 8 + j;
        int sw = ((t >> 3) & 3) << 5;
        uint32 pk;
        if (p == 0) {
          pk = packpair(u[j], v[j]);
        } else {
          float l0 = (u[j] - (float)(half_t)u[j]) * 2048.f;
          float l1 = (v[j] - (float)(half_t)v[j]) * 2048.f;
          pk = packpair(l0, l1);
        }
        *(uint32*)(sm + XS_OFF + t * 528 + ((c2 * 4) ^ sw)) = pk;
      }
    }
    __syncthreads();
    // ---- MFMA: this phase's 16 ks split over kh wave-pairs ----
    {
      int colt = nh * 32 + l31;
      int sw = ((colt >> 3) & 3) << 5;
      const char* xr = sm + XS_OFF + colt * 528;
#pragma unroll
      for (int ks = 0; ks < 8; ++ks) {
        int kg = kh * 8 + ks;
        halfx8 bf = *(const halfx8*)(xr + ((kg * 32 + lhi * 16) ^ sw));
        halfx8 hiA = *(const halfx8*)(WsS + l31 * 512 + kg * 16 + lhi * 8);
        if (p == 0) {
          accH = MFMA(hiA, bf, accH);
          halfx8 loA = *(const halfx8*)(WsS + l31 * 512 + 256 + kg * 16 + lhi * 8);
          accL = MFMA(loA, bf, accL);
        } else {
          accL = MFMA(hiA, bf, accL);
        }
      }
    }
    __syncthreads();
  }
  // ---- skb reduce over kh ----
  {
    float* skb = (float*)(sm + SKB_OFF) + kh * 32 * 68;
#pragma unroll
    for (int r = 0; r < 16; ++r) {
      int row = (r & 3) + 8 * (r >> 2) + 4 * lhi;
      skb[row * 68 + nh * 32 + l31] = accH[r] + accL[r] * (1.f / 2048.f);
    }
  }
  __syncthreads();
  {
    int cth = tid >> 3, twh = (tid & 7) * 8;
    const float* s0 = (const float*)(sm + SKB_OFF) + cth * 68 + twh;
    const float* s1 = s0 + 32 * 68;
    float* rp = res + ((size_t)b * 32 + cth) * T_LEN + t0 + twh;
#pragma unroll
    for (int vq = 0; vq < 8; vq += 4) {
      float4 sa = *(const float4*)(s0 + vq);
      float4 sb = *(const float4*)(s1 + vq);
      float4 o;
      o.x = sa.x + sb.x;
      o.y = sa.y + sb.y;
      o.z = sa.z + sb.z;
      o.w = sa.w + sb.w;
      *(float4*)(rp + vq) = o;
    }
  }
}

// ---------------- fused WaveNet layer: 2 barriers/tile, prefetch pipeline ----------------
// LDS: zT 64 x 272B at 0 (17408); skb 2x32x68 f32 at 17408 (17408); total 34816
#define LOAD_TILE(TI, CV, PV)                                              \
  {                                                                        \
    int tl_ = blockIdx.x + (TI) * LGRID;                                   \
    int bb_ = tl_ / NTILE;                                                 \
    int tb_ = (tl_ - bb_ * NTILE) * TT;                                    \
    const float* rip_ = resIn + ((size_t)bb_ * 32 + cth) * T_LEN;          \
    *(float4*)(CV)       = *(const float4*)(rip_ + tb_ + twh);             \
    *(float4*)((CV) + 4) = *(const float4*)(rip_ + tb_ + twh + 4);         \
    int tp_ = tb_ + twh - d;                                               \
    if (tp_ >= 0 && (d & 3) == 0) {                                        \
      *(float4*)(PV)       = *(const float4*)(rip_ + tp_);                 \
      *(float4*)((PV) + 4) = *(const float4*)(rip_ + tp_ + 4);             \
    } else {                                                               \
      _Pragma("unroll")                                                    \
      for (int j_ = 0; j_ < 8; ++j_) {                                     \
        int q_ = tp_ + j_;                                                 \
        (PV)[j_] = (q_ >= 0) ? rip_[q_] : 0.f;                             \
      }                                                                    \
    }                                                                      \
  }

#define STAGE_TILE(CV, PV)                                                 \
  {                                                                        \
    _Pragma("unroll")                                                      \
    for (int j = 0; j < 8; ++j) {                                          \
      int t = twh + j;                                                     \
      int sw = ((t >> 3) & 3) << 5;                                        \
      char* zrow = sm + t * 272;                                           \
      half_t p0 = (half_t)(PV)[j];                                         \
      half_t c0 = (half_t)(CV)[j];                                         \
      float pl = ((PV)[j] - (float)p0) * 2048.f;                           \
      float cl = ((CV)[j] - (float)c0) * 2048.f;                           \
      *(uint32*)(zrow + ((cth * 4) ^ sw))       = packpair((PV)[j], (CV)[j]); \
      *(uint32*)(zrow + ((cth * 4 + 128) ^ sw)) = packpair(pl, cl);        \
    }                                                                      \
  }

#define TILE_BODY(TI, CV, PV, NCV, NPV, PREF)                                  \
  {                                                                            \
    int tile = blockIdx.x + (TI) * LGRID;                                      \
    int b = tile / NTILE;                                                      \
    int t0 = (tile - b * NTILE) * TT;                                          \
    if (PREF) { LOAD_TILE((TI) + 1, NCV, NPV); }                               \
    /* ---- GEMM1: h[128,64] = Wa @ z ---- */                                  \
    f32x16 hi0{}, hi1{}, lo0{}, lo1{};                                         \
    {                                                                          \
      int colt = nh * 32 + l31;                                                \
      int sw = ((colt >> 3) & 3) << 5;                                         \
      const char* zr = sm + colt * 272;                                        \
      _Pragma("unroll")                                                        \
      for (int ks = 0; ks < 12; ++ks) {                                        \
        int brow = (ks < 4) ? ks * 16                                          \
                            : ((ks < 8) ? (ks & 3) * 16 + 64 : (ks & 3) * 16); \
        halfx8 bf = *(const halfx8*)(zr + ((brow * 2 + lhi * 16) ^ sw));       \
        if (ks < 4) {                                                          \
          hi0 = MFMA(a1h0[ks], bf, hi0);                                       \
          hi1 = MFMA(a1h1[ks], bf, hi1);                                       \
        } else if (ks < 8) {                                                   \
          lo0 = MFMA(a1h0[ks & 3], bf, lo0);                                   \
          lo1 = MFMA(a1h1[ks & 3], bf, lo1);                                   \
        } else {                                                               \
          lo0 = MFMA(a1l0[ks & 3], bf, lo0);                                   \
          lo1 = MFMA(a1l1[ks & 3], bf, lo1);                                   \
        }                                                                      \
      }                                                                        \
    }                                                                          \
    /* ---- gate -> GEMM2 B-fragments (registers) ---- */                      \
    halfx8 gh0a, gh0b, gl0a, gl0b, gh1a, gh1b, gl1a, gl1b;                     \
    _Pragma("unroll")                                                          \
    for (int r = 0; r < 16; ++r) {                                             \
      float ha = hi0[r] + lo0[r] * (1.f / 2048.f);                             \
      float hb = hi1[r] + lo1[r] * (1.f / 2048.f);                             \
      ha = fmaxf(ha, -30.f);                                                   \
      hb = fmaxf(hb, -30.f);                                                   \
      float ea = __expf(-ha), eb = __expf(-hb);                                \
      float ga = (1.f - ea) * __builtin_amdgcn_rcpf(1.f + ea * ea);            \
      float gb = (1.f - eb) * __builtin_amdgcn_rcpf(1.f + eb * eb);            \
      half_t ga0 = (half_t)ga;                                                 \
      half_t gb0 = (half_t)gb;                                                 \
      half_t ga1 = (half_t)((ga - (float)ga0) * 2048.f);                       \
      half_t gb1 = (half_t)((gb - (float)gb0) * 2048.f);                       \
      if (r < 8) {                                                             \
        gh0a[r] = ga0; gl0a[r] = ga1; gh1a[r] = gb0; gl1a[r] = gb1;            \
      } else {                                                                 \
        gh0b[r - 8] = ga0; gl0b[r - 8] = ga1;                                  \
        gh1b[r - 8] = gb0; gl1b[r - 8] = gb1;                                  \
      }                                                                        \
    }                                                                          \
    /* ---- GEMM2: skip partial, register operands ---- */                     \
    f32x16 shi{}, slo{};                                                       \
    shi = MFMA(wrHi[0], gh0a, shi);                                            \
    shi = MFMA(wrHi[1], gh0b, shi);                                            \
    shi = MFMA(wrHi[2], gh1a, shi);                                            \
    shi = MFMA(wrHi[3], gh1b, shi);                                            \
    slo = MFMA(wrHi[0], gl0a, slo);                                            \
    slo = MFMA(wrHi[1], gl0b, slo);                                            \
    slo = MFMA(wrHi[2], gl1a, slo);                                            \
    slo = MFMA(wrHi[3], gl1b, slo);                                            \
    slo = MFMA(wrLo[0], gh0a, slo);                                            \
    slo = MFMA(wrLo[1], gh0b, slo);                                            \
    slo = MFMA(wrLo[2], gh1a, slo);                                            \
    slo = MFMA(wrLo[3], gh1b, slo);                                            \
    /* ---- skb partials (own region, no barrier needed before write) ---- */  \
    {                                                                          \
      float* skb = (float*)(sm + SKB_OFF) + mh * 32 * 68;                      \
      _Pragma("unroll")                                                        \
      for (int r = 0; r < 16; ++r) {                                           \
        int row = (r & 3) + 8 * (r >> 2) + 4 * lhi;                            \
        skb[row * 68 + nh * 32 + l31] = shi[r] + slo[r] * (1.f / 2048.f);      \
      }                                                                        \
    }                                                                          \
    __syncthreads();                                                           \
    /* ---- writeout (reads skb) + stage next tile into zT ---- */             \
    {                                                                          \
      const float* s0 = (const float*)(sm + SKB_OFF) + cth * 68 + twh;         \
      const float* s1 = s0 + 32 * 68;                                          \
      size_t base = ((size_t)b * 32 + cth) * T_LEN + t0 + twh;                 \
      _Pragma("unroll")                                                        \
      for (int v = 0; v < 8; v += 4) {                                         \
        float4 sa = *(const float4*)(s0 + v);                                  \
        float4 sb = *(const float4*)(s1 + v);                                  \
        float4 o;                                                              \
        o.x = (CV)[v]     + sa.x + sb.x;                                       \
        o.y = (CV)[v + 1] + sa.y + sb.y;                                       \
        o.z = (CV)[v + 2] + sa.z + sb.z;                                       \
        o.w = (CV)[v + 3] + sa.w + sb.w;                                       \
        *(float4*)(resOut + base + v) = o;                                     \
      }                                                                        \
    }                                                                          \
    if (PREF) {                                                                \
      STAGE_TILE(NCV, NPV)                                                     \
      __syncthreads();                                                         \
    }                                                                          \
  }

__global__ __launch_bounds__(256, 2) void layer_k(const float* __restrict__ resIn,
                                                  float* __restrict__ resOut,
                                                  const half_t* __restrict__ WaL,
                                                  const half_t* __restrict__ WrL,
                                                  int d) {
  __shared__ __align__(16) char sm[34816];
  const int SKB_OFF = 17408;
  int tid = threadIdx.x;
  int wave = tid >> 6, lane = tid & 63;
  int l31 = lane & 31, lhi = lane >> 5;
  int mh = wave & 1, nh = wave >> 1;        // wave owns m-half mh, t-half nh
  int cth = tid >> 3, twh = (tid & 7) * 8;  // staging/writeout thread mapping

  // ---- per-layer weights into regs (persist across 4 tiles) ----
  halfx8 a1h0[4], a1l0[4], a1h1[4], a1l1[4];
  {
    const half_t* wa = WaL + (mh * 64 + l31) * 128 + lhi * 8;
#pragma unroll
    for (int j = 0; j < 4; ++j) {
      a1h0[j] = *(const halfx8*)(wa + j * 16);
      a1l0[j] = *(const halfx8*)(wa + 64 + j * 16);
      a1h1[j] = *(const halfx8*)(wa + 32 * 128 + j * 16);
      a1l1[j] = *(const halfx8*)(wa + 32 * 128 + 64 + j * 16);
    }
  }
  halfx8 wrHi[4], wrLo[4];
  {
    const half_t* wr = WrL + l31 * 256 + mh * 64 + lhi * 8;
#pragma unroll
    for (int q = 0; q < 4; ++q) {
      wrHi[q] = *(const halfx8*)(wr + q * 16);
      wrLo[q] = *(const halfx8*)(wr + 128 + q * 16);
    }
  }

  float cvA[8], pvA[8], cvB[8], pvB[8];
  LOAD_TILE(0, cvA, pvA);
  STAGE_TILE(cvA, pvA)
  __syncthreads();

  TILE_BODY(0, cvA, pvA, cvB, pvB, 1)
  TILE_BODY(1, cvB, pvB, cvA, pvA, 1)
  TILE_BODY(2, cvA, pvA, cvB, pvB, 1)
  TILE_BODY(3, cvB, pvB, cvA, pvA, 0)
}

// ---------------- end: relu(resF-res0) -> relu(We1@.) -> We2@. ----------------
// Activations single fp16 (non-recurrent), weights split-2. LDS 38912 -> 3 blocks/CU.
//   [0, 33792)      h2T [64 t][528B]   | alias [0,8704): h1f32 [32][68] f32
//   [33792, 38912)  h1T [64 t][80B]
__global__ __launch_bounds__(512, 6) void end_k(const float* __restrict__ resF,
                                                const float* __restrict__ res0,
                                                const half_t* __restrict__ We1S,
                                                const half_t* __restrict__ We2S,
                                                float* __restrict__ out) {
  __shared__ __align__(16) char sm[38912];
  const int H2T_OFF = 0, H1F_OFF = 0, H1T_OFF = 33792;
  int tid = threadIdx.x;
  int b = blockIdx.x / NTILE;
  int t0 = (blockIdx.x % NTILE) * TT;

  {
    int c = tid >> 4, tt4 = (tid & 15) * 4;
    size_t base = ((size_t)b * 32 + c) * T_LEN + t0 + tt4;
    float4 f = *(const float4*)(resF + base);
    float4 z = *(const float4*)(res0 + base);
    float* h1 = (float*)(sm + H1F_OFF) + c * 68 + tt4;
    h1[0] = fmaxf(f.x - z.x, 0.f);
    h1[1] = fmaxf(f.y - z.y, 0.f);
    h1[2] = fmaxf(f.z - z.z, 0.f);
    h1[3] = fmaxf(f.w - z.w, 0.f);
  }
  __syncthreads();
  {
    int t = tid & 63, cg2 = tid >> 6;
    const float* h1 = (const float*)(sm + H1F_OFF);
    halfx4 hi;
#pragma unroll
    for (int j = 0; j < 4; ++j) hi[j] = (half_t)h1[(cg2 * 4 + j) * 68 + t];
    *(halfx4*)(sm + H1T_OFF + t * 80 + cg2 * 8) = hi;
  }
  __syncthreads();

  int wave = tid >> 6, lane = tid & 63;
  int l31 = lane & 31, lhi = lane >> 5;

  // ---- e1: h2[256,64] = We1 @ h1 (weights split, B single) ----
  f32x16 aHi0{}, aHi1{}, aLo0{}, aLo1{};
  {
    const char* h1t = sm + H1T_OFF;
    const half_t* wp = We1S + (wave * 32 + l31) * 64;
#pragma unroll
    for (int ks = 0; ks < 2; ++ks) {
      halfx8 hiA = *(const halfx8*)(wp + ks * 16 + lhi * 8);
      halfx8 loA = *(const halfx8*)(wp + 32 + ks * 16 + lhi * 8);
      halfx8 B0 = *(const halfx8*)(h1t + l31 * 80 + (ks * 16 + lhi * 8) * 2);
      halfx8 B1 = *(const halfx8*)(h1t + (32 + l31) * 80 + (ks * 16 + lhi * 8) * 2);
      aHi0 = MFMA(hiA, B0, aHi0);
      aLo0 = MFMA(loA, B0, aLo0);
      aHi1 = MFMA(hiA, B1, aHi1);
      aLo1 = MFMA(loA, B1, aLo1);
    }
  }
  {
#pragma unroll
    for (int n = 0; n < 2; ++n) {
      const f32x16& aH = n ? aHi1 : aHi0;
      const f32x16& aL = n ? aLo1 : aLo0;
      int t = n * 32 + l31;
      half_t* row = (half_t*)(sm + H2T_OFF) + t * 264;
#pragma unroll
      for (int g = 0; g < 4; ++g) {
        halfx4 hi;
#pragma unroll
        for (int j = 0; j < 4; ++j) {
          int r = g * 4 + j;
          float v = fmaxf(aH[r] + aL[r] * (1.f / 2048.f), 0.f);
          hi[j] = (half_t)v;
        }
        *(halfx4*)(row + wave * 32 + g * 8 + lhi * 4) = hi;
      }
    }
  }
  __syncthreads();

  // ---- e2: out[256,64] = We2 @ h2 (weights split, B single) ----
  f32x16 bHi0{}, bHi1{}, bLo0{}, bLo1{};
  {
    const half_t* wp = We2S + (size_t)(wave * 32 + l31) * 512;
    const char* h2t = sm + H2T_OFF;
#pragma unroll 2
    for (int ks = 0; ks < 16; ++ks) {
      halfx8 hiA = *(const halfx8*)(wp + ks * 16 + lhi * 8);
      halfx8 loA = *(const halfx8*)(wp + 256 + ks * 16 + lhi * 8);
      halfx8 B0 = *(const halfx8*)(h2t + l31 * 528 + (ks * 16 + lhi * 8) * 2);
      halfx8 B1 = *(const halfx8*)(h2t + (32 + l31) * 528 + (ks * 16 + lhi * 8) * 2);
      bHi0 = MFMA(hiA, B0, bHi0);
      bLo0 = MFMA(loA, B0, bLo0);
      bHi1 = MFMA(hiA, B1, bHi1);
      bLo1 = MFMA(loA, B1, bLo1);
    }
  }
  {
#pragma unroll
    for (int n = 0; n < 2; ++n) {
      const f32x16& bH = n ? bHi1 : bHi0;
      const f32x16& bL = n ? bLo1 : bLo0;
      int t = t0 + n * 32 + l31;
#pragma unroll
      for (int r = 0; r < 16; ++r) {
        int o = wave * 32 + (r & 3) + 8 * (r >> 2) + 4 * lhi;
        out[((size_t)b * 256 + o) * T_LEN + t] = bH[r] + bL[r] * (1.f / 2048.f);
      }
    }
  }
}

extern "C" void kernel_launch(void* const* d_in, const int* in_sizes, int n_in,
                              void* d_out, int out_size, void* d_ws, size_t ws_size,
                              hipStream_t stream) {
  const float* x   = (const float*)d_in[0];
  const float* Wst = (const float*)d_in[1];
  const float* Wd  = (const float*)d_in[2];
  const float* Wr  = (const float*)d_in[3];
  const float* We1 = (const float*)d_in[4];
  const float* We2 = (const float*)d_in[5];
  float* out = (float*)d_out;
  float* ws = (float*)d_ws;

  float* resA = ws;                        // start output (skips = resF - resA)
  float* resB = resA + N_RES;
  float* resC = resB + N_RES;
  half_t* WaG  = (half_t*)(resC + N_RES);  // 40*16384
  half_t* WrG  = WaG + 40 * 16384;         // 40*8192
  half_t* WsS  = WrG + 40 * 8192;          // 16384
  half_t* We1S = WsS + 16384;              // 16384
  half_t* We2S = We1S + 16384;             // 131072

  repack_k<<<2560, 256, 0, stream>>>(Wd, Wr, Wst, We1, We2, WaG, WrG, WsS, We1S, We2S);
  start_k<<<NBLK, 256, 0, stream>>>(x, WsS, resA);

  const float* rin = resA;
  for (int l = 0; l < 40; ++l) {
    float* rout = (l & 1) ? resC : resB;
    layer_k<<<LGRID, 256, 0, stream>>>(rin, rout, WaG + l * 16384, WrG + l * 8192,
                                       1 << (l % 10));
    rin = rout;
  }
  end_k<<<NBLK, 512, 0, stream>>>(rin, resA, We1S, We2S, out);
}

// Round 10
// 1081.430 us; speedup vs baseline: 1.0141x; 1.0141x over previous
//
#include <hip/hip_runtime.h>
#include <math.h>

#define T_LEN 16000
#define NTILE 250          // time tiles per batch row (16000/64)
#define TT 64              // time tile
#define NBLK 2000          // 8 * 250
#define LGRID 500          // layer grid: 4 strided tiles per block

static const int N_RES = 8 * 32 * T_LEN;   // 4,096,000 floats per residual buffer

typedef _Float16 half_t;
typedef __attribute__((ext_vector_type(8))) _Float16 halfx8;
typedef __attribute__((ext_vector_type(4))) _Float16 halfx4;
typedef __attribute__((ext_vector_type(16))) float f32x16;
typedef unsigned int uint32;
typedef unsigned short ushort16;

#define MFMA(a, b, c) __builtin_amdgcn_mfma_f32_32x32x16_f16((a), (b), (c), 0, 0, 0)

static __device__ inline uint32 packpair(float a, float b) {
  half_t ha = (half_t)a, hb = (half_t)b;
  return (uint32)__builtin_bit_cast(ushort16, ha) |
         ((uint32)__builtin_bit_cast(ushort16, hb) << 16);
}

// ---------------- weight repack ----------------
// WaG[l][o=0..127][k=0..127]: k<64: k=2c+s -> hi(Wd[l][o][c][s]); k>=64: lo*2048 of same
// WrG[l][o2=0..31][k=0..255]: g-register perm; kk=k&127: ks=kk>>4, lh=(kk>>3)&1, j=kk&7;
//   mh=ks>>2, til=(ks>>1)&1, ab=ks&1; m = mh*64+til*32+ab*16+(j&3)+8*(j>>2)+4*lh
//   k<128 hi of Wr[l][m][o2]^T, k>=128 lo*2048  (GEMM2's B-operand = gate regs directly)
// WsS[o=0..31][k=0..511]: kk=k&255: chan=(kk>>1)+(kk&1)*128; k<256 hi Ws[o][chan], k>=256 lo*2048
// We1S[o][k=0..63]: k<32 hi We1[o][k], k>=32 lo*2048
// We2S[o][k=0..511]: k<256 hi We2[o][k], k>=256 lo*2048
__global__ __launch_bounds__(256) void repack_k(
    const float* __restrict__ Wd, const float* __restrict__ Wr,
    const float* __restrict__ Ws, const float* __restrict__ We1,
    const float* __restrict__ We2,
    half_t* __restrict__ WaG, half_t* __restrict__ WrG, half_t* __restrict__ WsS,
    half_t* __restrict__ We1S, half_t* __restrict__ We2S) {
  int i = blockIdx.x * 256 + threadIdx.x;
  if (i < 40 * 128 * 128) {
    int l = i >> 14, r = i & 16383, o = r >> 7, k = r & 127;
    int kk = k & 63, c = kk >> 1, s = kk & 1;
    float w = Wd[(((l * 128 + o) * 32 + c) << 1) + s];
    half_t w0 = (half_t)w;
    WaG[i] = (k < 64) ? w0 : (half_t)((w - (float)w0) * 2048.f);
  }
  if (i < 40 * 32 * 256) {
    int l = i >> 13, r = i & 8191, o2 = r >> 8, k = r & 255;
    int kk = k & 127;
    int ks = kk >> 4, lh = (kk >> 3) & 1, j = kk & 7;
    int mh = ks >> 2, til = (ks >> 1) & 1, ab = ks & 1;
    int m = mh * 64 + til * 32 + ab * 16 + (j & 3) + ((j >> 2) << 3) + lh * 4;
    float w = Wr[(l * 32 + o2) * 128 + m];
    half_t w0 = (half_t)w;
    WrG[i] = (k < 128) ? w0 : (half_t)((w - (float)w0) * 2048.f);
  }
  if (i < 16384) {
    int o = i >> 9, k = i & 511, kk = k & 255;
    int chan = (kk >> 1) + (kk & 1) * 128;
    float w = Ws[o * 256 + chan];
    half_t w0 = (half_t)w;
    WsS[i] = (k < 256) ? w0 : (half_t)((w - (float)w0) * 2048.f);
  }
  if (i < 16384) {
    int o = i >> 6, k = i & 63;
    float w = We1[o * 32 + (k & 31)];
    half_t w0 = (half_t)w;
    We1S[i] = (k < 32) ? w0 : (half_t)((w - (float)w0) * 2048.f);
  }
  if (i < 131072) {
    int o = i >> 9, k = i & 511;
    float w = We2[o * 256 + (k & 255)];
    half_t w0 = (half_t)w;
    We2S[i] = (k < 256) ? w0 : (half_t)((w - (float)w0) * 2048.f);
  }
}

// ---------------- start 1x1 conv, MFMA split-2, load-once coalesced ----------------
// LDS: xs [64 t][528B] (256 K-halves/phase + pad, XOR-swizzled) at 0; skb 2x32x68 f32 at 33792
__global__ __launch_bounds__(256, 3) void start_k(const float* __restrict__ x,
                                                  const half_t* __restrict__ WsS,
                                                  float* __restrict__ res) {
  __shared__ __align__(16) char sm[51200];
  const int XS_OFF = 0, SKB_OFF = 33792;
  int tid = threadIdx.x;
  int wave = tid >> 6, lane = tid & 63;
  int l31 = lane & 31, lhi = lane >> 5;
  int nh = wave & 1, kh = wave >> 1;
  int b = blockIdx.x / NTILE;
  int t0 = (blockIdx.x % NTILE) * TT;
  int cth = tid >> 3, twh = (tid & 7) * 8;

  // ---- load once: 4 chunks x (channel c, c+128) x 8 t, coalesced ----
  float xa0[8], xa1[8], xa2[8], xa3[8];
  float xb0[8], xb1[8], xb2[8], xb3[8];
#define LDX(CC, XA, XB)                                                     \
  {                                                                         \
    const float* p0 = x + ((size_t)b * 256 + (CC)*32 + cth) * T_LEN + t0 + twh; \
    const float* p1 = p0 + (size_t)128 * T_LEN;                             \
    *(float4*)&(XA)[0] = *(const float4*)p0;                                \
    *(float4*)&(XA)[4] = *(const float4*)(p0 + 4);                          \
    *(float4*)&(XB)[0] = *(const float4*)p1;                                \
    *(float4*)&(XB)[4] = *(const float4*)(p1 + 4);                          \
  }
  LDX(0, xa0, xb0) LDX(1, xa1, xb1) LDX(2, xa2, xb2) LDX(3, xa3, xb3)
#undef LDX

  f32x16 accH{}, accL{};
#pragma unroll
  for (int p = 0; p < 2; ++p) {
    // ---- stage phase p from regs: p=0 hi pairs, p=1 lo pairs ----
#define STX(CC, XA, XB)                                                       \
    _Pragma("unroll")                                                         \
    for (int j = 0; j < 8; ++j) {                                             \
      int t = twh + j;                                                        \
      int sw = ((t >> 3) & 3) << 5;                                           \
      uint32 pk;                                                              \
      if (p == 0) {                                                           \
        pk = packpair((XA)[j], (XB)[j]);                                      \
      } else {                                                                \
        float l0 = ((XA)[j] - (float)(half_t)(XA)[j]) * 2048.f;               \
        float l1 = ((XB)[j] - (float)(half_t)(XB)[j]) * 2048.f;               \
        pk = packpair(l0, l1);                                                \
      }                                                                       \
      *(uint32*)(sm + XS_OFF + t * 528 + ((((CC)*32 + cth) * 4) ^ sw)) = pk;  \
    }
    STX(0, xa0, xb0) STX(1, xa1, xb1) STX(2, xa2, xb2) STX(3, xa3, xb3)
#undef STX
    __syncthreads();
    // ---- MFMA: 16 K-steps split over kh wave-pairs ----
    {
      int colt = nh * 32 + l31;
      int sw = ((colt >> 3) & 3) << 5;
      const char* xr = sm + XS_OFF + colt * 528;
#pragma unroll
      for (int ks = 0; ks < 8; ++ks) {
        int kg = kh * 8 + ks;
        halfx8 bf = *(const halfx8*)(xr + ((kg * 32 + lhi * 16) ^ sw));
        halfx8 hiA = *(const halfx8*)(WsS + l31 * 512 + kg * 16 + lhi * 8);
        if (p == 0) {
          accH = MFMA(hiA, bf, accH);
          halfx8 loA = *(const halfx8*)(WsS + l31 * 512 + 256 + kg * 16 + lhi * 8);
          accL = MFMA(loA, bf, accL);
        } else {
          accL = MFMA(hiA, bf, accL);
        }
      }
    }
    __syncthreads();
  }
  // ---- skb reduce over kh ----
  {
    float* skb = (float*)(sm + SKB_OFF) + kh * 32 * 68;
#pragma unroll
    for (int r = 0; r < 16; ++r) {
      int row = (r & 3) + 8 * (r >> 2) + 4 * lhi;
      skb[row * 68 + nh * 32 + l31] = accH[r] + accL[r] * (1.f / 2048.f);
    }
  }
  __syncthreads();
  {
    const float* s0 = (const float*)(sm + SKB_OFF) + cth * 68 + twh;
    const float* s1 = s0 + 32 * 68;
    float* rp = res + ((size_t)b * 32 + cth) * T_LEN + t0 + twh;
#pragma unroll
    for (int vq = 0; vq < 8; vq += 4) {
      float4 sa = *(const float4*)(s0 + vq);
      float4 sb = *(const float4*)(s1 + vq);
      float4 o;
      o.x = sa.x + sb.x;
      o.y = sa.y + sb.y;
      o.z = sa.z + sb.z;
      o.w = sa.w + sb.w;
      *(float4*)(rp + vq) = o;
    }
  }
}

// ---------------- fused WaveNet layer: 2 barriers/tile, prefetch pipeline ----------------
// LDS: zT 64 x 272B at 0 (17408); skb 2x32x68 f32 at 17408 (17408); total 34816
#define LOAD_TILE(TI, CV, PV)                                              \
  {                                                                        \
    int tl_ = blockIdx.x + (TI) * LGRID;                                   \
    int bb_ = tl_ / NTILE;                                                 \
    int tb_ = (tl_ - bb_ * NTILE) * TT;                                    \
    const float* rip_ = resIn + ((size_t)bb_ * 32 + cth) * T_LEN;          \
    *(float4*)(CV)       = *(const float4*)(rip_ + tb_ + twh);             \
    *(float4*)((CV) + 4) = *(const float4*)(rip_ + tb_ + twh + 4);         \
    int tp_ = tb_ + twh - d;                                               \
    if (tp_ >= 0 && (d & 3) == 0) {                                        \
      *(float4*)(PV)       = *(const float4*)(rip_ + tp_);                 \
      *(float4*)((PV) + 4) = *(const float4*)(rip_ + tp_ + 4);             \
    } else {                                                               \
      _Pragma("unroll")                                                    \
      for (int j_ = 0; j_ < 8; ++j_) {                                     \
        int q_ = tp_ + j_;                                                 \
        (PV)[j_] = (q_ >= 0) ? rip_[q_] : 0.f;                             \
      }                                                                    \
    }                                                                      \
  }

#define STAGE_TILE(CV, PV)                                                 \
  {                                                                        \
    _Pragma("unroll")                                                      \
    for (int j = 0; j < 8; ++j) {                                          \
      int t = twh + j;                                                     \
      int sw = ((t >> 3) & 3) << 5;                                        \
      char* zrow = sm + t * 272;                                           \
      half_t p0 = (half_t)(PV)[j];                                         \
      half_t c0 = (half_t)(CV)[j];                                         \
      float pl = ((PV)[j] - (float)p0) * 2048.f;                           \
      float cl = ((CV)[j] - (float)c0) * 2048.f;                           \
      *(uint32*)(zrow + ((cth * 4) ^ sw))       = packpair((PV)[j], (CV)[j]); \
      *(uint32*)(zrow + ((cth * 4 + 128) ^ sw)) = packpair(pl, cl);        \
    }                                                                      \
  }

#define TILE_BODY(TI, CV, PV, NCV, NPV, PREF)                                  \
  {                                                                            \
    int tile = blockIdx.x + (TI) * LGRID;                                      \
    int b = tile / NTILE;                                                      \
    int t0 = (tile - b * NTILE) * TT;                                          \
    if (PREF) { LOAD_TILE((TI) + 1, NCV, NPV); }                               \
    /* ---- GEMM1: h[128,64] = Wa @ z ---- */                                  \
    f32x16 hi0{}, hi1{}, lo0{}, lo1{};                                         \
    {                                                                          \
      int colt = nh * 32 + l31;                                                \
      int sw = ((colt >> 3) & 3) << 5;                                         \
      const char* zr = sm + colt * 272;                                        \
      _Pragma("unroll")                                                        \
      for (int ks = 0; ks < 12; ++ks) {                                        \
        int brow = (ks < 4) ? ks * 16                                          \
                            : ((ks < 8) ? (ks & 3) * 16 + 64 : (ks & 3) * 16); \
        halfx8 bf = *(const halfx8*)(zr + ((brow * 2 + lhi * 16) ^ sw));       \
        if (ks < 4) {                                                          \
          hi0 = MFMA(a1h0[ks], bf, hi0);                                       \
          hi1 = MFMA(a1h1[ks], bf, hi1);                                       \
        } else if (ks < 8) {                                                   \
          lo0 = MFMA(a1h0[ks & 3], bf, lo0);                                   \
          lo1 = MFMA(a1h1[ks & 3], bf, lo1);                                   \
        } else {                                                               \
          lo0 = MFMA(a1l0[ks & 3], bf, lo0);                                   \
          lo1 = MFMA(a1l1[ks & 3], bf, lo1);                                   \
        }                                                                      \
      }                                                                        \
    }                                                                          \
    /* ---- gate -> GEMM2 B-fragments (registers) ---- */                      \
    halfx8 gh0a, gh0b, gl0a, gl0b, gh1a, gh1b, gl1a, gl1b;                     \
    _Pragma("unroll")                                                          \
    for (int r = 0; r < 16; ++r) {                                             \
      float ha = hi0[r] + lo0[r] * (1.f / 2048.f);                             \
      float hb = hi1[r] + lo1[r] * (1.f / 2048.f);                             \
      ha = fmaxf(ha, -30.f);                                                   \
      hb = fmaxf(hb, -30.f);                                                   \
      float ea = __expf(-ha), eb = __expf(-hb);                                \
      float ga = (1.f - ea) * __builtin_amdgcn_rcpf(1.f + ea * ea);            \
      float gb = (1.f - eb) * __builtin_amdgcn_rcpf(1.f + eb * eb);            \
      half_t ga0 = (half_t)ga;                                                 \
      half_t gb0 = (half_t)gb;                                                 \
      half_t ga1 = (half_t)((ga - (float)ga0) * 2048.f);                       \
      half_t gb1 = (half_t)((gb - (float)gb0) * 2048.f);                       \
      if (r < 8) {                                                             \
        gh0a[r] = ga0; gl0a[r] = ga1; gh1a[r] = gb0; gl1a[r] = gb1;            \
      } else {                                                                 \
        gh0b[r - 8] = ga0; gl0b[r - 8] = ga1;                                  \
        gh1b[r - 8] = gb0; gl1b[r - 8] = gb1;                                  \
      }                                                                        \
    }                                                                          \
    /* ---- GEMM2: skip partial, register operands ---- */                     \
    f32x16 shi{}, slo{};                                                       \
    shi = MFMA(wrHi[0], gh0a, shi);                                            \
    shi = MFMA(wrHi[1], gh0b, shi);                                            \
    shi = MFMA(wrHi[2], gh1a, shi);                                            \
    shi = MFMA(wrHi[3], gh1b, shi);                                            \
    slo = MFMA(wrHi[0], gl0a, slo);                                            \
    slo = MFMA(wrHi[1], gl0b, slo);                                            \
    slo = MFMA(wrHi[2], gl1a, slo);                                            \
    slo = MFMA(wrHi[3], gl1b, slo);                                            \
    slo = MFMA(wrLo[0], gh0a, slo);                                            \
    slo = MFMA(wrLo[1], gh0b, slo);                                            \
    slo = MFMA(wrLo[2], gh1a, slo);                                            \
    slo = MFMA(wrLo[3], gh1b, slo);                                            \
    /* ---- skb partials (own region) ---- */                                  \
    {                                                                          \
      float* skb = (float*)(sm + SKB_OFF) + mh * 32 * 68;                      \
      _Pragma("unroll")                                                        \
      for (int r = 0; r < 16; ++r) {                                           \
        int row = (r & 3) + 8 * (r >> 2) + 4 * lhi;                            \
        skb[row * 68 + nh * 32 + l31] = shi[r] + slo[r] * (1.f / 2048.f);      \
      }                                                                        \
    }                                                                          \
    __syncthreads();                                                           \
    /* ---- writeout (reads skb) + stage next tile into zT ---- */             \
    {                                                                          \
      const float* s0 = (const float*)(sm + SKB_OFF) + cth * 68 + twh;         \
      const float* s1 = s0 + 32 * 68;                                          \
      size_t base = ((size_t)b * 32 + cth) * T_LEN + t0 + twh;                 \
      _Pragma("unroll")                                                        \
      for (int v = 0; v < 8; v += 4) {                                         \
        float4 sa = *(const float4*)(s0 + v);                                  \
        float4 sb = *(const float4*)(s1 + v);                                  \
        float4 o;                                                              \
        o.x = (CV)[v]     + sa.x + sb.x;                                       \
        o.y = (CV)[v + 1] + sa.y + sb.y;                                       \
        o.z = (CV)[v + 2] + sa.z + sb.z;                                       \
        o.w = (CV)[v + 3] + sa.w + sb.w;                                       \
        *(float4*)(resOut + base + v) = o;                                     \
      }                                                                        \
    }                                                                          \
    if (PREF) {                                                                \
      STAGE_TILE(NCV, NPV)                                                     \
      __syncthreads();                                                         \
    }                                                                          \
  }

__global__ __launch_bounds__(256, 2) void layer_k(const float* __restrict__ resIn,
                                                  float* __restrict__ resOut,
                                                  const half_t* __restrict__ WaL,
                                                  const half_t* __restrict__ WrL,
                                                  int d) {
  __shared__ __align__(16) char sm[34816];
  const int SKB_OFF = 17408;
  int tid = threadIdx.x;
  int wave = tid >> 6, lane = tid & 63;
  int l31 = lane & 31, lhi = lane >> 5;
  int mh = wave & 1, nh = wave >> 1;        // wave owns m-half mh, t-half nh
  int cth = tid >> 3, twh = (tid & 7) * 8;  // staging/writeout thread mapping

  // ---- per-layer weights into regs (persist across 4 tiles) ----
  halfx8 a1h0[4], a1l0[4], a1h1[4], a1l1[4];
  {
    const half_t* wa = WaL + (mh * 64 + l31) * 128 + lhi * 8;
#pragma unroll
    for (int j = 0; j < 4; ++j) {
      a1h0[j] = *(const halfx8*)(wa + j * 16);
      a1l0[j] = *(const halfx8*)(wa + 64 + j * 16);
      a1h1[j] = *(const halfx8*)(wa + 32 * 128 + j * 16);
      a1l1[j] = *(const halfx8*)(wa + 32 * 128 + 64 + j * 16);
    }
  }
  halfx8 wrHi[4], wrLo[4];
  {
    const half_t* wr = WrL + l31 * 256 + mh * 64 + lhi * 8;
#pragma unroll
    for (int q = 0; q < 4; ++q) {
      wrHi[q] = *(const halfx8*)(wr + q * 16);
      wrLo[q] = *(const halfx8*)(wr + 128 + q * 16);
    }
  }

  float cvA[8], pvA[8], cvB[8], pvB[8];
  LOAD_TILE(0, cvA, pvA);
  STAGE_TILE(cvA, pvA)
  __syncthreads();

  TILE_BODY(0, cvA, pvA, cvB, pvB, 1)
  TILE_BODY(1, cvB, pvB, cvA, pvA, 1)
  TILE_BODY(2, cvA, pvA, cvB, pvB, 1)
  TILE_BODY(3, cvB, pvB, cvA, pvA, 0)
}

// ---------------- end: relu(resF-res0) -> relu(We1@.) -> We2@. ----------------
// Activations single fp16 (non-recurrent), weights split-2. LDS 38912 -> 3 blocks/CU.
//   [0, 33792)      h2T [64 t][528B]   | alias [0,8704): h1f32 [32][68] f32
//   [33792, 38912)  h1T [64 t][80B]
__global__ __launch_bounds__(512, 6) void end_k(const float* __restrict__ resF,
                                                const float* __restrict__ res0,
                                                const half_t* __restrict__ We1S,
                                                const half_t* __restrict__ We2S,
                                                float* __restrict__ out) {
  __shared__ __align__(16) char sm[38912];
  const int H2T_OFF = 0, H1F_OFF = 0, H1T_OFF = 33792;
  int tid = threadIdx.x;
  int b = blockIdx.x / NTILE;
  int t0 = (blockIdx.x % NTILE) * TT;

  {
    int c = tid >> 4, tt4 = (tid & 15) * 4;
    size_t base = ((size_t)b * 32 + c) * T_LEN + t0 + tt4;
    float4 f = *(const float4*)(resF + base);
    float4 z = *(const float4*)(res0 + base);
    float* h1 = (float*)(sm + H1F_OFF) + c * 68 + tt4;
    h1[0] = fmaxf(f.x - z.x, 0.f);
    h1[1] = fmaxf(f.y - z.y, 0.f);
    h1[2] = fmaxf(f.z - z.z, 0.f);
    h1[3] = fmaxf(f.w - z.w, 0.f);
  }
  __syncthreads();
  {
    int t = tid & 63, cg2 = tid >> 6;
    const float* h1 = (const float*)(sm + H1F_OFF);
    halfx4 hi;
#pragma unroll
    for (int j = 0; j < 4; ++j) hi[j] = (half_t)h1[(cg2 * 4 + j) * 68 + t];
    *(halfx4*)(sm + H1T_OFF + t * 80 + cg2 * 8) = hi;
  }
  __syncthreads();

  int wave = tid >> 6, lane = tid & 63;
  int l31 = lane & 31, lhi = lane >> 5;

  // ---- e1: h2[256,64] = We1 @ h1 (weights split, B single) ----
  f32x16 aHi0{}, aHi1{}, aLo0{}, aLo1{};
  {
    const char* h1t = sm + H1T_OFF;
    const half_t* wp = We1S + (wave * 32 + l31) * 64;
#pragma unroll
    for (int ks = 0; ks < 2; ++ks) {
      halfx8 hiA = *(const halfx8*)(wp + ks * 16 + lhi * 8);
      halfx8 loA = *(const halfx8*)(wp + 32 + ks * 16 + lhi * 8);
      halfx8 B0 = *(const halfx8*)(h1t + l31 * 80 + (ks * 16 + lhi * 8) * 2);
      halfx8 B1 = *(const halfx8*)(h1t + (32 + l31) * 80 + (ks * 16 + lhi * 8) * 2);
      aHi0 = MFMA(hiA, B0, aHi0);
      aLo0 = MFMA(loA, B0, aLo0);
      aHi1 = MFMA(hiA, B1, aHi1);
      aLo1 = MFMA(loA, B1, aLo1);
    }
  }
  {
#pragma unroll
    for (int n = 0; n < 2; ++n) {
      const f32x16& aH = n ? aHi1 : aHi0;
      const f32x16& aL = n ? aLo1 : aLo0;
      int t = n * 32 + l31;
      half_t* row = (half_t*)(sm + H2T_OFF) + t * 264;
#pragma unroll
      for (int g = 0; g < 4; ++g) {
        halfx4 hi;
#pragma unroll
        for (int j = 0; j < 4; ++j) {
          int r = g * 4 + j;
          float v = fmaxf(aH[r] + aL[r] * (1.f / 2048.f), 0.f);
          hi[j] = (half_t)v;
        }
        *(halfx4*)(row + wave * 32 + g * 8 + lhi * 4) = hi;
      }
    }
  }
  __syncthreads();

  // ---- e2: out[256,64] = We2 @ h2 (weights split, B single) ----
  f32x16 bHi0{}, bHi1{}, bLo0{}, bLo1{};
  {
    const half_t* wp = We2S + (size_t)(wave * 32 + l31) * 512;
    const char* h2t = sm + H2T_OFF;
#pragma unroll 2
    for (int ks = 0; ks < 16; ++ks) {
      halfx8 hiA = *(const halfx8*)(wp + ks * 16 + lhi * 8);
      halfx8 loA = *(const halfx8*)(wp + 256 + ks * 16 + lhi * 8);
      halfx8 B0 = *(const halfx8*)(h2t + l31 * 528 + (ks * 16 + lhi * 8) * 2);
      halfx8 B1 = *(const halfx8*)(h2t + (32 + l31) * 528 + (ks * 16 + lhi * 8) * 2);
      bHi0 = MFMA(hiA, B0, bHi0);
      bLo0 = MFMA(loA, B0, bLo0);
      bHi1 = MFMA(hiA, B1, bHi1);
      bLo1 = MFMA(loA, B1, bLo1);
    }
  }
  {
#pragma unroll
    for (int n = 0; n < 2; ++n) {
      const f32x16& bH = n ? bHi1 : bHi0;
      const f32x16& bL = n ? bLo1 : bLo0;
      int t = t0 + n * 32 + l31;
#pragma unroll
      for (int r = 0; r < 16; ++r) {
        int o = wave * 32 + (r & 3) + 8 * (r >> 2) + 4 * lhi;
        out[((size_t)b * 256 + o) * T_LEN + t] = bH[r] + bL[r] * (1.f / 2048.f);
      }
    }
  }
}

extern "C" void kernel_launch(void* const* d_in, const int* in_sizes, int n_in,
                              void* d_out, int out_size, void* d_ws, size_t ws_size,
                              hipStream_t stream) {
  const float* x   = (const float*)d_in[0];
  const float* Wst = (const float*)d_in[1];
  const float* Wd  = (const float*)d_in[2];
  const float* Wr  = (const float*)d_in[3];
  const float* We1 = (const float*)d_in[4];
  const float* We2 = (const float*)d_in[5];
  float* out = (float*)d_out;
  float* ws = (float*)d_ws;

  float* resA = ws;                        // start output (skips = resF - resA)
  float* resB = resA + N_RES;
  float* resC = resB + N_RES;
  half_t* WaG  = (half_t*)(resC + N_RES);  // 40*16384
  half_t* WrG  = WaG + 40 * 16384;         // 40*8192
  half_t* WsS  = WrG + 40 * 8192;          // 16384
  half_t* We1S = WsS + 16384;              // 16384
  half_t* We2S = We1S + 16384;             // 131072

  repack_k<<<2560, 256, 0, stream>>>(Wd, Wr, Wst, We1, We2, WaG, WrG, WsS, We1S, We2S);
  start_k<<<NBLK, 256, 0, stream>>>(x, WsS, resA);

  const float* rin = resA;
  for (int l = 0; l < 40; ++l) {
    float* rout = (l & 1) ? resC : resB;
    layer_k<<<LGRID, 256, 0, stream>>>(rin, rout, WaG + l * 16384, WrG + l * 8192,
                                       1 << (l % 10));
    rin = rout;
  }
  end_k<<<NBLK, 512, 0, stream>>>(rin, resA, We1S, We2S, out);
}

// Round 11
// 1054.326 us; speedup vs baseline: 1.0402x; 1.0257x over previous
//
#include <hip/hip_runtime.h>
#include <math.h>

#define T_LEN 16000
#define NTILE 250          // time tiles per batch row (16000/64)
#define TT 64              // time tile
#define NBLK 2000          // 8 * 250
#define LGRID 500          // layer grid: 4 strided tiles per block

static const int N_RES = 8 * 32 * T_LEN;   // 4,096,000 floats per residual buffer

typedef _Float16 half_t;
typedef __attribute__((ext_vector_type(8))) _Float16 halfx8;
typedef __attribute__((ext_vector_type(4))) _Float16 halfx4;
typedef __attribute__((ext_vector_type(16))) float f32x16;
typedef unsigned int uint32;
typedef unsigned short ushort16;

#define MFMA(a, b, c) __builtin_amdgcn_mfma_f32_32x32x16_f16((a), (b), (c), 0, 0, 0)

static __device__ inline uint32 packpair(float a, float b) {
  half_t ha = (half_t)a, hb = (half_t)b;
  return (uint32)__builtin_bit_cast(ushort16, ha) |
         ((uint32)__builtin_bit_cast(ushort16, hb) << 16);
}

// ---------------- weight repack ----------------
// WaG[l][o=0..127][k=0..127]: k<64: k=2c+s -> hi(Wd[l][o][c][s]); k>=64: lo*2048 of same
// WrG[l][o2=0..31][k=0..255]: g-register perm; kk=k&127: ks=kk>>4, lh=(kk>>3)&1, j=kk&7;
//   mh=ks>>2, til=(ks>>1)&1, ab=ks&1; m = mh*64+til*32+ab*16+(j&3)+8*(j>>2)+4*lh
//   k<128 hi of Wr[l][m][o2]^T, k>=128 lo*2048  (GEMM2's B-operand = gate regs directly)
// WsS[o=0..31][k=0..511]: kk=k&255: chan=(kk>>1)+(kk&1)*128; k<256 hi Ws[o][chan], k>=256 lo*2048
// We1S[o][k=0..63]: k<32 hi We1[o][k], k>=32 lo*2048
// We2S[o][k=0..511]: k<256 hi We2[o][k], k>=256 lo*2048
__global__ __launch_bounds__(256) void repack_k(
    const float* __restrict__ Wd, const float* __restrict__ Wr,
    const float* __restrict__ Ws, const float* __restrict__ We1,
    const float* __restrict__ We2,
    half_t* __restrict__ WaG, half_t* __restrict__ WrG, half_t* __restrict__ WsS,
    half_t* __restrict__ We1S, half_t* __restrict__ We2S) {
  int i = blockIdx.x * 256 + threadIdx.x;
  if (i < 40 * 128 * 128) {
    int l = i >> 14, r = i & 16383, o = r >> 7, k = r & 127;
    int kk = k & 63, c = kk >> 1, s = kk & 1;
    float w = Wd[(((l * 128 + o) * 32 + c) << 1) + s];
    half_t w0 = (half_t)w;
    WaG[i] = (k < 64) ? w0 : (half_t)((w - (float)w0) * 2048.f);
  }
  if (i < 40 * 32 * 256) {
    int l = i >> 13, r = i & 8191, o2 = r >> 8, k = r & 255;
    int kk = k & 127;
    int ks = kk >> 4, lh = (kk >> 3) & 1, j = kk & 7;
    int mh = ks >> 2, til = (ks >> 1) & 1, ab = ks & 1;
    int m = mh * 64 + til * 32 + ab * 16 + (j & 3) + ((j >> 2) << 3) + lh * 4;
    float w = Wr[(l * 32 + o2) * 128 + m];
    half_t w0 = (half_t)w;
    WrG[i] = (k < 128) ? w0 : (half_t)((w - (float)w0) * 2048.f);
  }
  if (i < 16384) {
    int o = i >> 9, k = i & 511, kk = k & 255;
    int chan = (kk >> 1) + (kk & 1) * 128;
    float w = Ws[o * 256 + chan];
    half_t w0 = (half_t)w;
    WsS[i] = (k < 256) ? w0 : (half_t)((w - (float)w0) * 2048.f);
  }
  if (i < 16384) {
    int o = i >> 6, k = i & 63;
    float w = We1[o * 32 + (k & 31)];
    half_t w0 = (half_t)w;
    We1S[i] = (k < 32) ? w0 : (half_t)((w - (float)w0) * 2048.f);
  }
  if (i < 131072) {
    int o = i >> 9, k = i & 511;
    float w = We2[o * 256 + (k & 255)];
    half_t w0 = (half_t)w;
    We2S[i] = (k < 256) ? w0 : (half_t)((w - (float)w0) * 2048.f);
  }
}

// ---------------- start 1x1 conv, MFMA split-2, chunk-streamed (no reg tile) ----------------
// LDS: xs [64 t][528B] (256 K-halves/phase + pad, XOR-swizzled) at 0; skb 2x32x68 f32 at 33792
// Phase 1 re-reads x from global: L2/L3-hot (x is L3-resident across graph replays).
__global__ __launch_bounds__(256, 2) void start_k(const float* __restrict__ x,
                                                  const half_t* __restrict__ WsS,
                                                  float* __restrict__ res) {
  __shared__ __align__(16) char sm[51200];
  const int XS_OFF = 0, SKB_OFF = 33792;
  int tid = threadIdx.x;
  int wave = tid >> 6, lane = tid & 63;
  int l31 = lane & 31, lhi = lane >> 5;
  int nh = wave & 1, kh = wave >> 1;
  int b = blockIdx.x / NTILE;
  int t0 = (blockIdx.x % NTILE) * TT;
  int cth = tid >> 3, twh = (tid & 7) * 8;

  f32x16 accH{}, accL{};
#pragma unroll
  for (int p = 0; p < 2; ++p) {
    // ---- stream 4 chunks: load (channel c, c+128) x 8t, pack phase p, store ----
#pragma unroll
    for (int cc = 0; cc < 4; ++cc) {
      const float* p0 = x + ((size_t)b * 256 + cc * 32 + cth) * T_LEN + t0 + twh;
      const float* p1 = p0 + (size_t)128 * T_LEN;
      float u[8], v[8];
      *(float4*)u       = *(const float4*)p0;
      *(float4*)(u + 4) = *(const float4*)(p0 + 4);
      *(float4*)v       = *(const float4*)p1;
      *(float4*)(v + 4) = *(const float4*)(p1 + 4);
#pragma unroll
      for (int j = 0; j < 8; ++j) {
        int t = twh + j;
        int sw = ((t >> 3) & 3) << 5;
        uint32 pk;
        if (p == 0) {
          pk = packpair(u[j], v[j]);
        } else {
          float l0 = (u[j] - (float)(half_t)u[j]) * 2048.f;
          float l1 = (v[j] - (float)(half_t)v[j]) * 2048.f;
          pk = packpair(l0, l1);
        }
        *(uint32*)(sm + XS_OFF + t * 528 + (((cc * 32 + cth) * 4) ^ sw)) = pk;
      }
    }
    __syncthreads();
    // ---- MFMA: 16 K-steps split over kh wave-pairs ----
    {
      int colt = nh * 32 + l31;
      int sw = ((colt >> 3) & 3) << 5;
      const char* xr = sm + XS_OFF + colt * 528;
#pragma unroll
      for (int ks = 0; ks < 8; ++ks) {
        int kg = kh * 8 + ks;
        halfx8 bf = *(const halfx8*)(xr + ((kg * 32 + lhi * 16) ^ sw));
        halfx8 hiA = *(const halfx8*)(WsS + l31 * 512 + kg * 16 + lhi * 8);
        if (p == 0) {
          accH = MFMA(hiA, bf, accH);
          halfx8 loA = *(const halfx8*)(WsS + l31 * 512 + 256 + kg * 16 + lhi * 8);
          accL = MFMA(loA, bf, accL);
        } else {
          accL = MFMA(hiA, bf, accL);
        }
      }
    }
    __syncthreads();
  }
  // ---- skb reduce over kh ----
  {
    float* skb = (float*)(sm + SKB_OFF) + kh * 32 * 68;
#pragma unroll
    for (int r = 0; r < 16; ++r) {
      int row = (r & 3) + 8 * (r >> 2) + 4 * lhi;
      skb[row * 68 + nh * 32 + l31] = accH[r] + accL[r] * (1.f / 2048.f);
    }
  }
  __syncthreads();
  {
    const float* s0 = (const float*)(sm + SKB_OFF) + cth * 68 + twh;
    const float* s1 = s0 + 32 * 68;
    float* rp = res + ((size_t)b * 32 + cth) * T_LEN + t0 + twh;
#pragma unroll
    for (int vq = 0; vq < 8; vq += 4) {
      float4 sa = *(const float4*)(s0 + vq);
      float4 sb = *(const float4*)(s1 + vq);
      float4 o;
      o.x = sa.x + sb.x;
      o.y = sa.y + sb.y;
      o.z = sa.z + sb.z;
      o.w = sa.w + sb.w;
      *(float4*)(rp + vq) = o;
    }
  }
}

// ---------------- fused WaveNet layer: 2 barriers/tile, prefetch pipeline ----------------
// LDS: zT 64 x 272B at 0 (17408); skb 2x32x68 f32 at 17408 (17408); total 34816
#define LOAD_TILE(TI, CV, PV)                                              \
  {                                                                        \
    int tl_ = blockIdx.x + (TI) * LGRID;                                   \
    int bb_ = tl_ / NTILE;                                                 \
    int tb_ = (tl_ - bb_ * NTILE) * TT;                                    \
    const float* rip_ = resIn + ((size_t)bb_ * 32 + cth) * T_LEN;          \
    *(float4*)(CV)       = *(const float4*)(rip_ + tb_ + twh);             \
    *(float4*)((CV) + 4) = *(const float4*)(rip_ + tb_ + twh + 4);         \
    int tp_ = tb_ + twh - d;                                               \
    if (tp_ >= 0 && (d & 3) == 0) {                                        \
      *(float4*)(PV)       = *(const float4*)(rip_ + tp_);                 \
      *(float4*)((PV) + 4) = *(const float4*)(rip_ + tp_ + 4);             \
    } else {                                                               \
      _Pragma("unroll")                                                    \
      for (int j_ = 0; j_ < 8; ++j_) {                                     \
        int q_ = tp_ + j_;                                                 \
        (PV)[j_] = (q_ >= 0) ? rip_[q_] : 0.f;                             \
      }                                                                    \
    }                                                                      \
  }

#define STAGE_TILE(CV, PV)                                                 \
  {                                                                        \
    _Pragma("unroll")                                                      \
    for (int j = 0; j < 8; ++j) {                                          \
      int t = twh + j;                                                     \
      int sw = ((t >> 3) & 3) << 5;                                        \
      char* zrow = sm + t * 272;                                           \
      half_t p0 = (half_t)(PV)[j];                                         \
      half_t c0 = (half_t)(CV)[j];                                         \
      float pl = ((PV)[j] - (float)p0) * 2048.f;                           \
      float cl = ((CV)[j] - (float)c0) * 2048.f;                           \
      *(uint32*)(zrow + ((cth * 4) ^ sw))       = packpair((PV)[j], (CV)[j]); \
      *(uint32*)(zrow + ((cth * 4 + 128) ^ sw)) = packpair(pl, cl);        \
    }                                                                      \
  }

#define TILE_BODY(TI, CV, PV, NCV, NPV, PREF)                                  \
  {                                                                            \
    int tile = blockIdx.x + (TI) * LGRID;                                      \
    int b = tile / NTILE;                                                      \
    int t0 = (tile - b * NTILE) * TT;                                          \
    if (PREF) { LOAD_TILE((TI) + 1, NCV, NPV); }                               \
    /* ---- GEMM1: h[128,64] = Wa @ z ---- */                                  \
    f32x16 hi0{}, hi1{}, lo0{}, lo1{};                                         \
    {                                                                          \
      int colt = nh * 32 + l31;                                                \
      int sw = ((colt >> 3) & 3) << 5;                                         \
      const char* zr = sm + colt * 272;                                        \
      _Pragma("unroll")                                                        \
      for (int ks = 0; ks < 12; ++ks) {                                        \
        int brow = (ks < 4) ? ks * 16                                          \
                            : ((ks < 8) ? (ks & 3) * 16 + 64 : (ks & 3) * 16); \
        halfx8 bf = *(const halfx8*)(zr + ((brow * 2 + lhi * 16) ^ sw));       \
        if (ks < 4) {                                                          \
          hi0 = MFMA(a1h0[ks], bf, hi0);                                       \
          hi1 = MFMA(a1h1[ks], bf, hi1);                                       \
        } else if (ks < 8) {                                                   \
          lo0 = MFMA(a1h0[ks & 3], bf, lo0);                                   \
          lo1 = MFMA(a1h1[ks & 3], bf, lo1);                                   \
        } else {                                                               \
          lo0 = MFMA(a1l0[ks & 3], bf, lo0);                                   \
          lo1 = MFMA(a1l1[ks & 3], bf, lo1);                                   \
        }                                                                      \
      }                                                                        \
    }                                                                          \
    /* ---- gate -> GEMM2 B-fragments (registers) ---- */                      \
    halfx8 gh0a, gh0b, gl0a, gl0b, gh1a, gh1b, gl1a, gl1b;                     \
    _Pragma("unroll")                                                          \
    for (int r = 0; r < 16; ++r) {                                             \
      float ha = hi0[r] + lo0[r] * (1.f / 2048.f);                             \
      float hb = hi1[r] + lo1[r] * (1.f / 2048.f);                             \
      ha = fmaxf(ha, -30.f);                                                   \
      hb = fmaxf(hb, -30.f);                                                   \
      float ea = __expf(-ha), eb = __expf(-hb);                                \
      float ga = (1.f - ea) * __builtin_amdgcn_rcpf(1.f + ea * ea);            \
      float gb = (1.f - eb) * __builtin_amdgcn_rcpf(1.f + eb * eb);            \
      half_t ga0 = (half_t)ga;                                                 \
      half_t gb0 = (half_t)gb;                                                 \
      half_t ga1 = (half_t)((ga - (float)ga0) * 2048.f);                       \
      half_t gb1 = (half_t)((gb - (float)gb0) * 2048.f);                       \
      if (r < 8) {                                                             \
        gh0a[r] = ga0; gl0a[r] = ga1; gh1a[r] = gb0; gl1a[r] = gb1;            \
      } else {                                                                 \
        gh0b[r - 8] = ga0; gl0b[r - 8] = ga1;                                  \
        gh1b[r - 8] = gb0; gl1b[r - 8] = gb1;                                  \
      }                                                                        \
    }                                                                          \
    /* ---- GEMM2: skip partial, register operands ---- */                     \
    f32x16 shi{}, slo{};                                                       \
    shi = MFMA(wrHi[0], gh0a, shi);                                            \
    shi = MFMA(wrHi[1], gh0b, shi);                                            \
    shi = MFMA(wrHi[2], gh1a, shi);                                            \
    shi = MFMA(wrHi[3], gh1b, shi);                                            \
    slo = MFMA(wrHi[0], gl0a, slo);                                            \
    slo = MFMA(wrHi[1], gl0b, slo);                                            \
    slo = MFMA(wrHi[2], gl1a, slo);                                            \
    slo = MFMA(wrHi[3], gl1b, slo);                                            \
    slo = MFMA(wrLo[0], gh0a, slo);                                            \
    slo = MFMA(wrLo[1], gh0b, slo);                                            \
    slo = MFMA(wrLo[2], gh1a, slo);                                            \
    slo = MFMA(wrLo[3], gh1b, slo);                                            \
    /* ---- skb partials (own region) ---- */                                  \
    {                                                                          \
      float* skb = (float*)(sm + SKB_OFF) + mh * 32 * 68;                      \
      _Pragma("unroll")                                                        \
      for (int r = 0; r < 16; ++r) {                                           \
        int row = (r & 3) + 8 * (r >> 2) + 4 * lhi;                            \
        skb[row * 68 + nh * 32 + l31] = shi[r] + slo[r] * (1.f / 2048.f);      \
      }                                                                        \
    }                                                                          \
    __syncthreads();                                                           \
    /* ---- writeout (reads skb) + stage next tile into zT ---- */             \
    {                                                                          \
      const float* s0 = (const float*)(sm + SKB_OFF) + cth * 68 + twh;         \
      const float* s1 = s0 + 32 * 68;                                          \
      size_t base = ((size_t)b * 32 + cth) * T_LEN + t0 + twh;                 \
      _Pragma("unroll")                                                        \
      for (int v = 0; v < 8; v += 4) {                                         \
        float4 sa = *(const float4*)(s0 + v);                                  \
        float4 sb = *(const float4*)(s1 + v);                                  \
        float4 o;                                                              \
        o.x = (CV)[v]     + sa.x + sb.x;                                       \
        o.y = (CV)[v + 1] + sa.y + sb.y;                                       \
        o.z = (CV)[v + 2] + sa.z + sb.z;                                       \
        o.w = (CV)[v + 3] + sa.w + sb.w;                                       \
        *(float4*)(resOut + base + v) = o;                                     \
      }                                                                        \
    }                                                                          \
    if (PREF) {                                                                \
      STAGE_TILE(NCV, NPV)                                                     \
      __syncthreads();                                                         \
    }                                                                          \
  }

__global__ __launch_bounds__(256, 2) void layer_k(const float* __restrict__ resIn,
                                                  float* __restrict__ resOut,
                                                  const half_t* __restrict__ WaL,
                                                  const half_t* __restrict__ WrL,
                                                  int d) {
  __shared__ __align__(16) char sm[34816];
  const int SKB_OFF = 17408;
  int tid = threadIdx.x;
  int wave = tid >> 6, lane = tid & 63;
  int l31 = lane & 31, lhi = lane >> 5;
  int mh = wave & 1, nh = wave >> 1;        // wave owns m-half mh, t-half nh
  int cth = tid >> 3, twh = (tid & 7) * 8;  // staging/writeout thread mapping

  // ---- per-layer weights into regs (persist across 4 tiles) ----
  halfx8 a1h0[4], a1l0[4], a1h1[4], a1l1[4];
  {
    const half_t* wa = WaL + (mh * 64 + l31) * 128 + lhi * 8;
#pragma unroll
    for (int j = 0; j < 4; ++j) {
      a1h0[j] = *(const halfx8*)(wa + j * 16);
      a1l0[j] = *(const halfx8*)(wa + 64 + j * 16);
      a1h1[j] = *(const halfx8*)(wa + 32 * 128 + j * 16);
      a1l1[j] = *(const halfx8*)(wa + 32 * 128 + 64 + j * 16);
    }
  }
  halfx8 wrHi[4], wrLo[4];
  {
    const half_t* wr = WrL + l31 * 256 + mh * 64 + lhi * 8;
#pragma unroll
    for (int q = 0; q < 4; ++q) {
      wrHi[q] = *(const halfx8*)(wr + q * 16);
      wrLo[q] = *(const halfx8*)(wr + 128 + q * 16);
    }
  }

  float cvA[8], pvA[8], cvB[8], pvB[8];
  LOAD_TILE(0, cvA, pvA);
  STAGE_TILE(cvA, pvA)
  __syncthreads();

  TILE_BODY(0, cvA, pvA, cvB, pvB, 1)
  TILE_BODY(1, cvB, pvB, cvA, pvA, 1)
  TILE_BODY(2, cvA, pvA, cvB, pvB, 1)
  TILE_BODY(3, cvB, pvB, cvA, pvA, 0)
}

// ---------------- end: relu(resF-res0) -> relu(We1@.) -> We2@. ----------------
// Activations single fp16 (non-recurrent), weights split-2. LDS 38912 -> 3 blocks/CU.
//   [0, 33792)      h2T [64 t][528B]   | alias [0,8704): h1f32 [32][68] f32
//   [33792, 38912)  h1T [64 t][80B]
__global__ __launch_bounds__(512, 6) void end_k(const float* __restrict__ resF,
                                                const float* __restrict__ res0,
                                                const half_t* __restrict__ We1S,
                                                const half_t* __restrict__ We2S,
                                                float* __restrict__ out) {
  __shared__ __align__(16) char sm[38912];
  const int H2T_OFF = 0, H1F_OFF = 0, H1T_OFF = 33792;
  int tid = threadIdx.x;
  int b = blockIdx.x / NTILE;
  int t0 = (blockIdx.x % NTILE) * TT;

  {
    int c = tid >> 4, tt4 = (tid & 15) * 4;
    size_t base = ((size_t)b * 32 + c) * T_LEN + t0 + tt4;
    float4 f = *(const float4*)(resF + base);
    float4 z = *(const float4*)(res0 + base);
    float* h1 = (float*)(sm + H1F_OFF) + c * 68 + tt4;
    h1[0] = fmaxf(f.x - z.x, 0.f);
    h1[1] = fmaxf(f.y - z.y, 0.f);
    h1[2] = fmaxf(f.z - z.z, 0.f);
    h1[3] = fmaxf(f.w - z.w, 0.f);
  }
  __syncthreads();
  {
    int t = tid & 63, cg2 = tid >> 6;
    const float* h1 = (const float*)(sm + H1F_OFF);
    halfx4 hi;
#pragma unroll
    for (int j = 0; j < 4; ++j) hi[j] = (half_t)h1[(cg2 * 4 + j) * 68 + t];
    *(halfx4*)(sm + H1T_OFF + t * 80 + cg2 * 8) = hi;
  }
  __syncthreads();

  int wave = tid >> 6, lane = tid & 63;
  int l31 = lane & 31, lhi = lane >> 5;

  // ---- e1: h2[256,64] = We1 @ h1 (weights split, B single) ----
  f32x16 aHi0{}, aHi1{}, aLo0{}, aLo1{};
  {
    const char* h1t = sm + H1T_OFF;
    const half_t* wp = We1S + (wave * 32 + l31) * 64;
#pragma unroll
    for (int ks = 0; ks < 2; ++ks) {
      halfx8 hiA = *(const halfx8*)(wp + ks * 16 + lhi * 8);
      halfx8 loA = *(const halfx8*)(wp + 32 + ks * 16 + lhi * 8);
      halfx8 B0 = *(const halfx8*)(h1t + l31 * 80 + (ks * 16 + lhi * 8) * 2);
      halfx8 B1 = *(const halfx8*)(h1t + (32 + l31) * 80 + (ks * 16 + lhi * 8) * 2);
      aHi0 = MFMA(hiA, B0, aHi0);
      aLo0 = MFMA(loA, B0, aLo0);
      aHi1 = MFMA(hiA, B1, aHi1);
      aLo1 = MFMA(loA, B1, aLo1);
    }
  }
  {
#pragma unroll
    for (int n = 0; n < 2; ++n) {
      const f32x16& aH = n ? aHi1 : aHi0;
      const f32x16& aL = n ? aLo1 : aLo0;
      int t = n * 32 + l31;
      half_t* row = (half_t*)(sm + H2T_OFF) + t * 264;
#pragma unroll
      for (int g = 0; g < 4; ++g) {
        halfx4 hi;
#pragma unroll
        for (int j = 0; j < 4; ++j) {
          int r = g * 4 + j;
          float v = fmaxf(aH[r] + aL[r] * (1.f / 2048.f), 0.f);
          hi[j] = (half_t)v;
        }
        *(halfx4*)(row + wave * 32 + g * 8 + lhi * 4) = hi;
      }
    }
  }
  __syncthreads();

  // ---- e2: out[256,64] = We2 @ h2 (weights split, B single) ----
  f32x16 bHi0{}, bHi1{}, bLo0{}, bLo1{};
  {
    const half_t* wp = We2S + (size_t)(wave * 32 + l31) * 512;
    const char* h2t = sm + H2T_OFF;
#pragma unroll 2
    for (int ks = 0; ks < 16; ++ks) {
      halfx8 hiA = *(const halfx8*)(wp + ks * 16 + lhi * 8);
      halfx8 loA = *(const halfx8*)(wp + 256 + ks * 16 + lhi * 8);
      halfx8 B0 = *(const halfx8*)(h2t + l31 * 528 + (ks * 16 + lhi * 8) * 2);
      halfx8 B1 = *(const halfx8*)(h2t + (32 + l31) * 528 + (ks * 16 + lhi * 8) * 2);
      bHi0 = MFMA(hiA, B0, bHi0);
      bLo0 = MFMA(loA, B0, bLo0);
      bHi1 = MFMA(hiA, B1, bHi1);
      bLo1 = MFMA(loA, B1, bLo1);
    }
  }
  {
#pragma unroll
    for (int n = 0; n < 2; ++n) {
      const f32x16& bH = n ? bHi1 : bHi0;
      const f32x16& bL = n ? bLo1 : bLo0;
      int t = t0 + n * 32 + l31;
#pragma unroll
      for (int r = 0; r < 16; ++r) {
        int o = wave * 32 + (r & 3) + 8 * (r >> 2) + 4 * lhi;
        out[((size_t)b * 256 + o) * T_LEN + t] = bH[r] + bL[r] * (1.f / 2048.f);
      }
    }
  }
}

extern "C" void kernel_launch(void* const* d_in, const int* in_sizes, int n_in,
                              void* d_out, int out_size, void* d_ws, size_t ws_size,
                              hipStream_t stream) {
  const float* x   = (const float*)d_in[0];
  const float* Wst = (const float*)d_in[1];
  const float* Wd  = (const float*)d_in[2];
  const float* Wr  = (const float*)d_in[3];
  const float* We1 = (const float*)d_in[4];
  const float* We2 = (const float*)d_in[5];
  float* out = (float*)d_out;
  float* ws = (float*)d_ws;

  float* resA = ws;                        // start output (skips = resF - resA)
  float* resB = resA + N_RES;
  float* resC = resB + N_RES;
  half_t* WaG  = (half_t*)(resC + N_RES);  // 40*16384
  half_t* WrG  = WaG + 40 * 16384;         // 40*8192
  half_t* WsS  = WrG + 40 * 8192;          // 16384
  half_t* We1S = WsS + 16384;              // 16384
  half_t* We2S = We1S + 16384;             // 131072

  repack_k<<<2560, 256, 0, stream>>>(Wd, Wr, Wst, We1, We2, WaG, WrG, WsS, We1S, We2S);
  start_k<<<NBLK, 256, 0, stream>>>(x, WsS, resA);

  const float* rin = resA;
  for (int l = 0; l < 40; ++l) {
    float* rout = (l & 1) ? resC : resB;
    layer_k<<<LGRID, 256, 0, stream>>>(rin, rout, WaG + l * 16384, WrG + l * 8192,
                                       1 << (l % 10));
    rin = rout;
  }
  end_k<<<NBLK, 512, 0, stream>>>(rin, resA, We1S, We2S, out);
}